// Round 1
// baseline (696.726 us; speedup 1.0000x reference)
//
#include <hip/hip_runtime.h>
#include <math.h>

#define BN_EPS 1e-5f

// ---------------- CSR build ----------------

__global__ void count_kernel(const int* __restrict__ dst, int* __restrict__ cnt, int e) {
  int i = blockIdx.x * 256 + threadIdx.x;
  int stride = gridDim.x * 256;
  for (; i < e; i += stride) atomicAdd(&cnt[dst[i]], 1);
}

__global__ void dinv_kernel(const int* __restrict__ cnt, float* __restrict__ dinv, int n) {
  int i = blockIdx.x * 256 + threadIdx.x;
  if (i < n) dinv[i] = rsqrtf((float)(cnt[i] + 1));  // +1 self loop
}

__global__ void scan_block_sums(const int* __restrict__ cnt, int* __restrict__ partial, int n) {
  __shared__ int sdata[256];
  int base = blockIdx.x * 1024;
  int s = 0;
  for (int i = threadIdx.x; i < 1024; i += 256) {
    int idx = base + i;
    s += (idx < n) ? cnt[idx] : 0;
  }
  sdata[threadIdx.x] = s;
  __syncthreads();
  for (int off = 128; off > 0; off >>= 1) {
    if (threadIdx.x < off) sdata[threadIdx.x] += sdata[threadIdx.x + off];
    __syncthreads();
  }
  if (threadIdx.x == 0) partial[blockIdx.x] = sdata[0];
}

__global__ void scan_partials(int* __restrict__ partial, int nb,
                              int* __restrict__ row_start, int n, int e) {
  if (blockIdx.x == 0 && threadIdx.x == 0) {
    int acc = 0;
    for (int i = 0; i < nb; i++) { int v = partial[i]; partial[i] = acc; acc += v; }
    row_start[n] = e;
  }
}

__global__ void scan_write(const int* __restrict__ cnt, const int* __restrict__ partial,
                           int* __restrict__ row_start, int* __restrict__ cursor, int n) {
  __shared__ int tsum[256];
  int base = blockIdx.x * 1024 + threadIdx.x * 4;
  int v[4]; int s = 0;
#pragma unroll
  for (int j = 0; j < 4; j++) { int idx = base + j; v[j] = (idx < n) ? cnt[idx] : 0; s += v[j]; }
  tsum[threadIdx.x] = s;
  __syncthreads();
  for (int off = 1; off < 256; off <<= 1) {
    int add = (threadIdx.x >= off) ? tsum[threadIdx.x - off] : 0;
    __syncthreads();
    tsum[threadIdx.x] += add;
    __syncthreads();
  }
  int excl = partial[blockIdx.x] + ((threadIdx.x > 0) ? tsum[threadIdx.x - 1] : 0);
#pragma unroll
  for (int j = 0; j < 4; j++) {
    int idx = base + j;
    if (idx < n) { row_start[idx] = excl; cursor[idx] = excl; }
    excl += v[j];
  }
}

__global__ void fill_kernel(const int* __restrict__ src, const int* __restrict__ dst,
                            int* __restrict__ cursor, int* __restrict__ csr_src, int e) {
  int i = blockIdx.x * 256 + threadIdx.x;
  int stride = gridDim.x * 256;
  for (; i < e; i += stride) {
    int p = atomicAdd(&cursor[dst[i]], 1);
    csr_src[p] = src[i];
  }
}

// ---------------- per-layer kernels ----------------

// hh[n,c] = dinv[n] * sum_k X[n,k] * W[k,c]
template <int K, int C, int LOGC>
__global__ void matmul_dinv(const float* __restrict__ X, const float* __restrict__ W,
                            const float* __restrict__ dinv, float* __restrict__ hh, int n) {
  __shared__ float w[K * C];
  for (int i = threadIdx.x; i < K * C; i += 256) w[i] = W[i];
  __syncthreads();
  int tid = blockIdx.x * 256 + threadIdx.x;
  int total = n * C;
  int stride = gridDim.x * 256;
  for (int idx = tid; idx < total; idx += stride) {
    int nn = idx >> LOGC;
    int c = idx & (C - 1);
    float acc = 0.f;
#pragma unroll
    for (int k = 0; k < K; k++) acc += X[nn * K + k] * w[k * C + c];
    hh[idx] = acc * dinv[nn];
  }
}

// act[n,c] = relu(dinv[n]*(hh[n,c] + sum_{j in row(n)} hh[src_j,c]) + b[c])
// also accumulates per-channel sum / sumsq for BatchNorm into stats[0..C) / stats[C..2C)
template <int C, int LOGC>
__global__ void gather_finalize(const float* __restrict__ hh, const int* __restrict__ row_start,
                                const int* __restrict__ csr_src, const float* __restrict__ dinv,
                                const float* __restrict__ bias, float* __restrict__ act,
                                float* __restrict__ stats, int n) {
  constexpr int NPB = 256 >> LOGC;
  int tid = threadIdx.x;
  int c = tid & (C - 1);
  int local = tid >> LOGC;
  float lsum = 0.f, lsq = 0.f;
  for (int n0 = blockIdx.x * NPB + local; n0 < n; n0 += gridDim.x * NPB) {
    float acc = hh[n0 * C + c];
    int s = row_start[n0], e0 = row_start[n0 + 1];
    for (int j = s; j < e0; j++) {
      int srcn = csr_src[j];
      acc += hh[srcn * C + c];
    }
    float v = dinv[n0] * acc + bias[c];
    v = v > 0.f ? v : 0.f;   // ReLU
    act[n0 * C + c] = v;
    lsum += v;
    lsq += v * v;
  }
  __shared__ float red[512];
  red[tid] = lsum;
  red[256 + tid] = lsq;
  __syncthreads();
  for (int off = 128; off >= C; off >>= 1) {
    if (tid < off) {
      red[tid] += red[tid + off];
      red[256 + tid] += red[256 + tid + off];
    }
    __syncthreads();
  }
  if (tid < C) {
    atomicAdd(&stats[tid], red[tid]);
    atomicAdd(&stats[C + tid], red[256 + tid]);
  }
}

// y = elu((v - mean)*rsqrt(var+eps)*g + bt), in place
template <int C>
__global__ void bn_elu(float* __restrict__ act, const float* __restrict__ stats,
                       const float* __restrict__ g, const float* __restrict__ bt, int n) {
  int tid = blockIdx.x * 256 + threadIdx.x;
  int total = n * C;
  int stride = gridDim.x * 256;
  float inv_n = 1.0f / (float)n;
  for (int i = tid; i < total; i += stride) {
    int c = i & (C - 1);
    float m = stats[c] * inv_n;
    float var = stats[C + c] * inv_n - m * m;
    var = fmaxf(var, 0.f);
    float sc = rsqrtf(var + BN_EPS) * g[c];
    float v = (act[i] - m) * sc + bt[c];
    act[i] = v > 0.f ? v : (expf(v) - 1.f);  // ELU
  }
}

// ---------------- MLP head + log_softmax ----------------

__global__ void head_kernel(const float* __restrict__ h,
                            const float* __restrict__ Wf1, const float* __restrict__ bf1,
                            const float* __restrict__ Wf2, const float* __restrict__ bf2,
                            const float* __restrict__ Wf3, const float* __restrict__ bf3,
                            float* __restrict__ out, int n) {
  __shared__ float w1[64 * 32], w2[32 * 16], w3[16 * 2];
  __shared__ float sb1[32], sb2[16], sb3[2];
  for (int i = threadIdx.x; i < 64 * 32; i += 256) w1[i] = Wf1[i];
  for (int i = threadIdx.x; i < 32 * 16; i += 256) w2[i] = Wf2[i];
  if (threadIdx.x < 32) {
    w3[threadIdx.x] = Wf3[threadIdx.x];
    sb1[threadIdx.x] = bf1[threadIdx.x];
  }
  if (threadIdx.x < 16) sb2[threadIdx.x] = bf2[threadIdx.x];
  if (threadIdx.x < 2) sb3[threadIdx.x] = bf3[threadIdx.x];
  __syncthreads();

  int n0 = blockIdx.x * 256 + threadIdx.x;
  if (n0 >= n) return;

  float hv[64];
#pragma unroll
  for (int k = 0; k < 64; k++) hv[k] = h[n0 * 64 + k];

  float a1[32];
#pragma unroll
  for (int c = 0; c < 32; c++) {
    float acc = sb1[c];
#pragma unroll
    for (int k = 0; k < 64; k++) acc += hv[k] * w1[k * 32 + c];
    a1[c] = acc > 0.f ? acc : (expf(acc) - 1.f);
  }
  float a2[16];
#pragma unroll
  for (int c = 0; c < 16; c++) {
    float acc = sb2[c];
#pragma unroll
    for (int k = 0; k < 32; k++) acc += a1[k] * w2[k * 16 + c];
    a2[c] = acc > 0.f ? acc : (expf(acc) - 1.f);
  }
  float z0 = sb3[0], z1 = sb3[1];
#pragma unroll
  for (int k = 0; k < 16; k++) {
    z0 += a2[k] * w3[k * 2 + 0];
    z1 += a2[k] * w3[k * 2 + 1];
  }
  float mx = fmaxf(z0, z1);
  float lse = mx + logf(expf(z0 - mx) + expf(z1 - mx));
  out[n0 * 2 + 0] = z0 - lse;
  out[n0 * 2 + 1] = z1 - lse;
}

// ---------------- launch ----------------

extern "C" void kernel_launch(void* const* d_in, const int* in_sizes, int n_in,
                              void* d_out, int out_size, void* d_ws, size_t ws_size,
                              hipStream_t stream) {
  const float* x = (const float*)d_in[0];
  const int* ei = (const int*)d_in[1];
  const float* W1 = (const float*)d_in[2];  const float* b1 = (const float*)d_in[3];
  const float* g1 = (const float*)d_in[4];  const float* bt1 = (const float*)d_in[5];
  const float* W2 = (const float*)d_in[6];  const float* b2 = (const float*)d_in[7];
  const float* g2 = (const float*)d_in[8];  const float* bt2 = (const float*)d_in[9];
  const float* W3 = (const float*)d_in[10]; const float* b3 = (const float*)d_in[11];
  const float* g3 = (const float*)d_in[12]; const float* bt3 = (const float*)d_in[13];
  const float* Wf1 = (const float*)d_in[14]; const float* bf1 = (const float*)d_in[15];
  const float* Wf2 = (const float*)d_in[16]; const float* bf2 = (const float*)d_in[17];
  const float* Wf3 = (const float*)d_in[18]; const float* bf3 = (const float*)d_in[19];
  float* out = (float*)d_out;

  const int N = in_sizes[0] / 4;
  const int E = in_sizes[1] / 2;
  const int* srcp = ei;
  const int* dstp = ei + E;
  const int NB = (N + 1023) / 1024;

  char* ws = (char*)d_ws;
  size_t off = 0;
  auto alloc = [&](size_t bytes) {
    off = (off + 255) & ~(size_t)255;
    size_t o = off;
    off += bytes;
    return o;
  };
  int*   cnt       = (int*)  (ws + alloc((size_t)N * 4));
  float* dinv      = (float*)(ws + alloc((size_t)N * 4));
  int*   row_start = (int*)  (ws + alloc((size_t)(N + 1) * 4));
  int*   cursor    = (int*)  (ws + alloc((size_t)N * 4));
  int*   partial   = (int*)  (ws + alloc((size_t)NB * 4));
  int*   csr_src   = (int*)  (ws + alloc((size_t)E * 4));
  float* stats     = (float*)(ws + alloc((size_t)224 * 4));  // 2*16 + 2*32 + 2*64
  float* bufA      = (float*)(ws + alloc((size_t)N * 64 * 4));
  float* bufB      = (float*)(ws + alloc((size_t)N * 64 * 4));
  float* st1 = stats;       // [32]
  float* st2 = stats + 32;  // [64]
  float* st3 = stats + 96;  // [128]

  hipMemsetAsync(cnt, 0, (size_t)N * 4, stream);
  hipMemsetAsync(stats, 0, 224 * 4, stream);

  int eb = (E + 255) / 256;
  int nb256 = (N + 255) / 256;

  count_kernel<<<eb, 256, 0, stream>>>(dstp, cnt, E);
  dinv_kernel<<<nb256, 256, 0, stream>>>(cnt, dinv, N);
  scan_block_sums<<<NB, 256, 0, stream>>>(cnt, partial, N);
  scan_partials<<<1, 64, 0, stream>>>(partial, NB, row_start, N, E);
  scan_write<<<NB, 256, 0, stream>>>(cnt, partial, row_start, cursor, N);
  fill_kernel<<<eb, 256, 0, stream>>>(srcp, dstp, cursor, csr_src, E);

  // Layer 1: [N,4] -> [N,16]
  matmul_dinv<4, 16, 4><<<(N * 16 + 255) / 256, 256, 0, stream>>>(x, W1, dinv, bufA, N);
  gather_finalize<16, 4><<<1024, 256, 0, stream>>>(bufA, row_start, csr_src, dinv, b1, bufB, st1, N);
  bn_elu<16><<<(N * 16 + 255) / 256, 256, 0, stream>>>(bufB, st1, g1, bt1, N);

  // Layer 2: [N,16] -> [N,32]
  matmul_dinv<16, 32, 5><<<(N * 32 + 255) / 256, 256, 0, stream>>>(bufB, W2, dinv, bufA, N);
  gather_finalize<32, 5><<<1024, 256, 0, stream>>>(bufA, row_start, csr_src, dinv, b2, bufB, st2, N);
  bn_elu<32><<<(N * 32 + 255) / 256, 256, 0, stream>>>(bufB, st2, g2, bt2, N);

  // Layer 3: [N,32] -> [N,64]
  matmul_dinv<32, 64, 6><<<(N * 64 + 255) / 256, 256, 0, stream>>>(bufB, W3, dinv, bufA, N);
  gather_finalize<64, 6><<<1024, 256, 0, stream>>>(bufA, row_start, csr_src, dinv, b3, bufB, st3, N);
  bn_elu<64><<<(N * 64 + 255) / 256, 256, 0, stream>>>(bufB, st3, g3, bt3, N);

  // MLP head + log_softmax
  head_kernel<<<nb256, 256, 0, stream>>>(bufB, Wf1, bf1, Wf2, bf2, Wf3, bf3, out, N);
}